// Round 4
// baseline (613.033 us; speedup 1.0000x reference)
//
#include <hip/hip_runtime.h>
#include <hip/hip_bf16.h>

#define HW 3136      // 56*56
#define CTOT 64
#define NTOT 128
#define BB 16
#define TTT 8

// ---------- helpers ----------
static __device__ __forceinline__ float bf2f(unsigned short u) {
    union { unsigned int ui; float f; } v;
    v.ui = ((unsigned int)u) << 16;
    return v.f;
}
static __device__ __forceinline__ unsigned short f2bf(float f) {
    union { float f; unsigned int u; } v;
    v.f = f;
    unsigned int u = v.u;
    unsigned int r = (u + 0x7fffu + ((u >> 16) & 1u)) >> 16;  // round-nearest-even
    return (unsigned short)r;
}

// ---------- K1: attn = sigmoid(relu(conv2d(x))) FUSED with stats + x2-bf16 store
//               + last-block inline finalize (scale/shift) ----------
// Block 128 = 8 chunks(8ch) x 16 quads; grid = n(128) * tile(49).
__global__ __launch_bounds__(128) void k_attn(const float* __restrict__ x,
                                              const float* __restrict__ aw,
                                              const float* __restrict__ ab,
                                              const float* __restrict__ gamma,
                                              const float* __restrict__ beta,
                                              float* __restrict__ attn,
                                              unsigned short* __restrict__ x2,
                                              float* __restrict__ stats,
                                              unsigned int* __restrict__ counter,
                                              float* __restrict__ ss) {
    const int tile = blockIdx.x % 49;
    const int n = blockIdx.x / 49;
    const int chunk = threadIdx.x >> 4;    // 0..7
    const int qi = threadIdx.x & 15;       // 0..15
    const int quad = tile * 16 + qi;       // 0..783
    const int q = quad % 14;
    const int h = quad / 14;
    const int w0 = q * 4;

    __shared__ float wl[2304];             // weights [c][dh][kw][head]
    __shared__ float l[8][16][17];         // chunk-reduce scratch (reused for stats)
    __shared__ float4 abuf[4][16];         // attn broadcast [head][quad-in-tile]

    const float* xn = x + (size_t)n * CTOT * HW;
    const int c0 = chunk * 8;

    // branchless row loader: clamped address + validity mask, address-select edges
    auto loadrows = [&](int c, float r[3][6]) {
#pragma unroll
        for (int dh = 0; dh < 3; ++dh) {
            const int hh = h + dh - 1;
            const bool v = (hh >= 0) && (hh < 56);
            const float* row = xn + c * HW + (v ? hh : h) * 56 + w0;
            const float m = v ? 1.f : 0.f;
            const float4 mid = *(const float4*)row;
            const float e0 = row[(q > 0) ? -1 : 0] * ((q > 0) ? m : 0.f);
            const float e5 = row[(q < 13) ? 4 : 3] * ((q < 13) ? m : 0.f);
            r[dh][0] = e0;
            r[dh][1] = mid.x * m; r[dh][2] = mid.y * m;
            r[dh][3] = mid.z * m; r[dh][4] = mid.w * m;
            r[dh][5] = e5;
        }
    };

    float bufA[3][6], bufB[3][6];
    loadrows(c0, bufA);                    // prologue load in flight during staging

    // gather attn weights into LDS, permuted to [c][dh][kw][head]
#pragma unroll
    for (int i = 0; i < 18; ++i) {
        const int idx = threadIdx.x + i * 128;     // 2304 exact
        const int hd = idx & 3;
        const int kw = (idx >> 2) % 3;
        const int dh = (idx / 12) % 3;
        const int c = idx / 36;
        wl[idx] = aw[hd * 576 + c * 9 + dh * 3 + kw];
    }
    __syncthreads();

    float acc[4][4];
#pragma unroll
    for (int hd = 0; hd < 4; ++hd)
#pragma unroll
        for (int j = 0; j < 4; ++j) acc[hd][j] = 0.f;

    float midst[8][4];                     // central-row stash for stats / x2

#pragma unroll
    for (int i = 0; i < 8; ++i) {
        float (*cur)[6] = (i & 1) ? bufB : bufA;
        float (*nxt)[6] = (i & 1) ? bufA : bufB;
        if (i < 7) loadrows(c0 + i + 1, nxt);   // prefetch next channel

        midst[i][0] = cur[1][1]; midst[i][1] = cur[1][2];
        midst[i][2] = cur[1][3]; midst[i][3] = cur[1][4];

        const int c = c0 + i;
#pragma unroll
        for (int dh = 0; dh < 3; ++dh) {
            const float* wb = &wl[c * 36 + dh * 12];
            const float4 wk0 = *(const float4*)(wb);
            const float4 wk1 = *(const float4*)(wb + 4);
            const float4 wk2 = *(const float4*)(wb + 8);
#pragma unroll
            for (int j = 0; j < 4; ++j) {
                const float a0 = cur[dh][j], a1 = cur[dh][j + 1], a2 = cur[dh][j + 2];
                acc[0][j] = fmaf(a0, wk0.x, fmaf(a1, wk1.x, fmaf(a2, wk2.x, acc[0][j])));
                acc[1][j] = fmaf(a0, wk0.y, fmaf(a1, wk1.y, fmaf(a2, wk2.y, acc[1][j])));
                acc[2][j] = fmaf(a0, wk0.z, fmaf(a1, wk1.z, fmaf(a2, wk2.z, acc[2][j])));
                acc[3][j] = fmaf(a0, wk0.w, fmaf(a1, wk1.w, fmaf(a2, wk2.w, acc[3][j])));
            }
        }
    }

    // chunk-reduce attn accumulators through LDS
    float* mine = &l[chunk][qi][0];
#pragma unroll
    for (int hd = 0; hd < 4; ++hd)
#pragma unroll
        for (int j = 0; j < 4; ++j) mine[hd * 4 + j] = acc[hd][j];
    __syncthreads();

    if (threadIdx.x < 64) {
        const int hd = threadIdx.x >> 4;
        const int rq = threadIdx.x & 15;
        float s0 = ab[hd], s1 = s0, s2 = s0, s3 = s0;
#pragma unroll
        for (int cch = 0; cch < 8; ++cch) {
            const float* p = &l[cch][rq][hd * 4];
            s0 += p[0]; s1 += p[1]; s2 += p[2]; s3 += p[3];
        }
        float4 o;
        o.x = s0 > 0.f ? 1.f / (1.f + __expf(-s0)) : 0.5f;
        o.y = s1 > 0.f ? 1.f / (1.f + __expf(-s1)) : 0.5f;
        o.z = s2 > 0.f ? 1.f / (1.f + __expf(-s2)) : 0.5f;
        o.w = s3 > 0.f ? 1.f / (1.f + __expf(-s3)) : 0.5f;
        *(float4*)(attn + (size_t)(n * 4 + hd) * HW + (tile * 16 + rq) * 4) = o;
        abuf[hd][rq] = o;
    }
    __syncthreads();

    // ---- fused: x2 = x*attn for this thread's 8 channels x 4 central pixels ----
    const int head = chunk >> 1;           // all 8 channels of a thread share one head
    const float4 a4 = abuf[head][qi];
    float s[8], sq[8];
#pragma unroll
    for (int i = 0; i < 8; ++i) {
        const float v0 = midst[i][0] * a4.x;
        const float v1 = midst[i][1] * a4.y;
        const float v2 = midst[i][2] * a4.z;
        const float v3 = midst[i][3] * a4.w;
        ushort4 o;
        o.x = f2bf(v0); o.y = f2bf(v1); o.z = f2bf(v2); o.w = f2bf(v3);
        *(ushort4*)(x2 + (size_t)(n * 64 + c0 + i) * HW + quad * 4) = o;
        s[i] = v0 + v1 + v2 + v3;
        sq[i] = v0 * v0 + v1 * v1 + v2 * v2 + v3 * v3;
    }
    // per-chunk reduce over the 16 qi threads via LDS (reuse l)
#pragma unroll
    for (int i = 0; i < 8; ++i) { mine[i] = s[i]; mine[8 + i] = sq[i]; }
    __syncthreads();
    {
        const int ch2 = threadIdx.x >> 4;  // chunk being reduced
        const int k = threadIdx.x & 15;    // 0..7 = sum, 8..15 = sumsq
        float t = 0.f;
#pragma unroll
        for (int qq = 0; qq < 16; ++qq) t += l[ch2][qq][k];
        const int cc = ch2 * 8 + (k & 7);
        const int rep = blockIdx.x & 15;
        atomicAdd(&stats[rep * 128 + (k >> 3) * 64 + cc], t);
    }

    // ---- last-block inline finalize: scale/shift from stats ----
    __syncthreads();   // barrier drains vmcnt -> all stats atomics of this block at L2
    __shared__ unsigned int winflag;
    if (threadIdx.x == 0) {
        __threadfence();
        winflag = (atomicAdd(counter, 1u) == gridDim.x - 1) ? 1u : 0u;
    }
    __syncthreads();
    if (winflag && threadIdx.x < 64) {
        const int c = threadIdx.x;
        float S = 0.f, Q = 0.f;
#pragma unroll
        for (int r = 0; r < 16; ++r) {
            S += atomicAdd(&stats[r * 128 + c], 0.f);        // device-scope atomic read
            Q += atomicAdd(&stats[r * 128 + 64 + c], 0.f);
        }
        const float cnt = 401408.0f;  // 128*3136
        const float mean = S / cnt;
        const float var = Q / cnt - mean * mean;
        const float scale = gamma[c] * rsqrtf(var + 1e-5f);
        ss[c] = scale;
        ss[64 + c] = beta[c] - mean * scale;
    }
}

// ---------- K2: in-place x2 <- bf16(relu(bn(x2))) ----------
// grid 12544 x 256, one uint4 (8 bf16) per thread; 392 uint4 per plane exactly.
__global__ __launch_bounds__(256) void k_bnr(unsigned int* __restrict__ x2u,
                                             const float* __restrict__ ss) {
    const int idx = blockIdx.x * 256 + threadIdx.x;   // 3211264 exact
    const int plane = idx / 392;                       // n*64 + c
    const int c = plane & 63;
    const float sc = ss[c], sh = ss[64 + c];
    uint4 v = ((const uint4*)x2u)[idx];
    unsigned int* p = (unsigned int*)&v;
#pragma unroll
    for (int i = 0; i < 4; ++i) {
        const float lo = fmaxf(fmaf(bf2f((unsigned short)(p[i] & 0xffffu)), sc, sh), 0.f);
        const float hi = fmaxf(fmaf(bf2f((unsigned short)(p[i] >> 16)), sc, sh), 0.f);
        p[i] = (unsigned int)f2bf(lo) | ((unsigned int)f2bf(hi) << 16);
    }
    ((uint4*)x2u)[idx] = v;
}

// ---------- K5: grouped conv3d + bias + tanh -> gate (LDS chunk-reduction) ----------
// Round-1 structure (best measured: 58us) + weights staged in LDS for codegen
// stability. Input x2 already = bf16(relu(bn(x*attn))).
// Block 128 = 8 ic-chunks x 16 quads. Grid = b(16) * oc(2) * tile(49).
__global__ __launch_bounds__(128) void k_conv3d(const unsigned short* __restrict__ x2,
                                                const float* __restrict__ w3,
                                                const float* __restrict__ b3,
                                                float* __restrict__ gate) {
    const int tile = blockIdx.x % 49;
    const int oc = (blockIdx.x / 49) & 1;
    const int b = blockIdx.x / 98;
    const int chunk = threadIdx.x >> 4;    // 0..7
    const int qi = threadIdx.x & 15;       // 0..15
    const int quad = tile * 16 + qi;       // 0..783
    const int q = quad % 14;
    const int h = quad / 14;
    const int w0 = q * 4;

    __shared__ float wlds[864];            // this oc's 32 ic x 27 weights
    for (int i = threadIdx.x; i < 864; i += 128) wlds[i] = w3[oc * 864 + i];
    __syncthreads();

    float acc[8][4];
#pragma unroll
    for (int t = 0; t < 8; ++t)
#pragma unroll
        for (int j = 0; j < 4; ++j) acc[t][j] = 0.f;

    const int ic0 = chunk * 4;
    for (int ic = ic0; ic < ic0 + 4; ++ic) {
        const int c = oc * 32 + ic;
        const unsigned short* cbase = x2 + (size_t)(b * 8 * 64 + c) * HW;
        const float* wic = &wlds[ic * 27];  // (dt, dh, dw)
#pragma unroll
        for (int tt = 0; tt < 8; ++tt) {
            const unsigned short* plane = cbase + (size_t)tt * (64 * HW);
#pragma unroll
            for (int dh = 0; dh < 3; ++dh) {
                const int hh = h + dh - 1;
                if (hh < 0 || hh >= 56) continue;
                const unsigned short* row = plane + hh * 56 + w0;
                const ushort4 mid = *(const ushort4*)row;
                const float f0 = (q > 0) ? bf2f(row[-1]) : 0.f;
                const float f1 = bf2f(mid.x), f2 = bf2f(mid.y);
                const float f3 = bf2f(mid.z), f4 = bf2f(mid.w);
                const float f5 = (q < 13) ? bf2f(row[4]) : 0.f;
#pragma unroll
                for (int dt = 0; dt < 3; ++dt) {
                    const int t = tt + 1 - dt;   // out[t] += in[t+dt-1]*w[dt]
                    if (t < 0 || t > 7) continue;
                    const float* wp = wic + dt * 9 + dh * 3;
                    const float wa = wp[0], wb = wp[1], wc = wp[2];
                    acc[t][0] = fmaf(f0, wa, fmaf(f1, wb, fmaf(f2, wc, acc[t][0])));
                    acc[t][1] = fmaf(f1, wa, fmaf(f2, wb, fmaf(f3, wc, acc[t][1])));
                    acc[t][2] = fmaf(f2, wa, fmaf(f3, wb, fmaf(f4, wc, acc[t][2])));
                    acc[t][3] = fmaf(f3, wa, fmaf(f4, wb, fmaf(f5, wc, acc[t][3])));
                }
            }
        }
    }

    // LDS reduction over chunks. Layout: [chunk][qi][9 float4] (pad 8->9 breaks bank alias)
    __shared__ float4 l4[8 * 16 * 9];
    float4* mine = &l4[(chunk * 16 + qi) * 9];
#pragma unroll
    for (int t = 0; t < 8; ++t) {
        float4 v;
        v.x = acc[t][0]; v.y = acc[t][1]; v.z = acc[t][2]; v.w = acc[t][3];
        mine[t] = v;
    }
    __syncthreads();

    const int rt = threadIdx.x >> 4;   // t of this thread's output
    const int rq = threadIdx.x & 15;   // quad within tile
    float4 s = l4[(0 * 16 + rq) * 9 + rt];
#pragma unroll
    for (int c = 1; c < 8; ++c) {
        const float4 v = l4[(c * 16 + rq) * 9 + rt];
        s.x += v.x; s.y += v.y; s.z += v.z; s.w += v.w;
    }
    const float bb = b3[oc];
    float4 o;
    o.x = tanhf(s.x + bb);
    o.y = tanhf(s.y + bb);
    o.z = tanhf(s.z + bb);
    o.w = tanhf(s.w + bb);
    const int outquad = tile * 16 + rq;
    *(float4*)(gate + (size_t)((b * 2 + oc) * 8 + rt) * HW + outquad * 4) = o;
}

// ---------- K6: final gating + temporal shift + interleave ----------
// Block = (b, h, head-pair): 448 threads = 32 co x 14 q, grid = 16*56*2 = 1792.
// All threads share grp (gate reuse x32) and two heads (attn reuse x16).
__global__ __launch_bounds__(448) void k_final(const float* __restrict__ x,
                                               const float* __restrict__ attn,
                                               const float* __restrict__ gate,
                                               float* __restrict__ out) {
    const int hg = blockIdx.x & 1;          // head-pair group == grp
    const int h = (blockIdx.x >> 1) % 56;
    const int b = blockIdx.x / 112;
    const int q = threadIdx.x % 14;
    const int col = threadIdx.x / 14;       // 0..31
    const int co = hg * 32 + col;
    const int sp = h * 56 + q * 4;

    int cs;
    if (co < 32) {
        cs = ((co & 1) << 4) | (co >> 1);
    } else {
        const int cc = co - 32;
        cs = 32 + (((cc & 1) << 4) | (cc >> 1));
    }
    const int grp = hg;
    const int head = cs >> 4;

    float4 x2v[8], g[8];
#pragma unroll
    for (int t = 0; t < 8; ++t) {
        const int n = b * 8 + t;
        const float4 xv = *(const float4*)(x + (size_t)(n * 64 + cs) * HW + sp);
        const float4 av = *(const float4*)(attn + (size_t)(n * 4 + head) * HW + sp);
        const float4 gv = *(const float4*)(gate + (size_t)((b * 2 + grp) * 8 + t) * HW + sp);
        x2v[t].x = xv.x * av.x;
        x2v[t].y = xv.y * av.y;
        x2v[t].z = xv.z * av.z;
        x2v[t].w = xv.w * av.w;
        g[t] = gv;
    }
#pragma unroll
    for (int t = 0; t < 8; ++t) {
        float4 o;
        o.x = x2v[t].x * (1.f - g[t].x);
        o.y = x2v[t].y * (1.f - g[t].y);
        o.z = x2v[t].z * (1.f - g[t].z);
        o.w = x2v[t].w * (1.f - g[t].w);
        if (grp == 0) {
            if (t < 7) {
                o.x += x2v[t + 1].x * g[t + 1].x;
                o.y += x2v[t + 1].y * g[t + 1].y;
                o.z += x2v[t + 1].z * g[t + 1].z;
                o.w += x2v[t + 1].w * g[t + 1].w;
            }
        } else {
            if (t > 0) {
                o.x += x2v[t - 1].x * g[t - 1].x;
                o.y += x2v[t - 1].y * g[t - 1].y;
                o.z += x2v[t - 1].z * g[t - 1].z;
                o.w += x2v[t - 1].w * g[t - 1].w;
            }
        }
        *(float4*)(out + (size_t)((b * 8 + t) * 64 + co) * HW + sp) = o;
    }
}

// ---------- launch ----------
extern "C" void kernel_launch(void* const* d_in, const int* in_sizes, int n_in,
                              void* d_out, int out_size, void* d_ws, size_t ws_size,
                              hipStream_t stream) {
    const float* x = (const float*)d_in[0];
    const float* aw = (const float*)d_in[1];
    const float* ab = (const float*)d_in[2];
    const float* gamma = (const float*)d_in[3];
    const float* beta = (const float*)d_in[4];
    const float* w3 = (const float*)d_in[5];
    const float* b3 = (const float*)d_in[6];
    float* out = (float*)d_out;

    char* ws = (char*)d_ws;
    // layout: x2 bf16 [0, 51380224) | attn f32 | gate f32 (stats+counter alias its
    // head; lifetimes disjoint: stats/counter dead before k_conv3d writes gate) | ss
    unsigned short* x2 = (unsigned short*)ws;
    float* attn = (float*)(ws + 51380224);            // 128*4*3136 f32 = 6422528 B
    float* gate = (float*)(ws + 57802752);            // 16*2*8*3136 f32 = 3211264 B
    float* stats = (float*)(ws + 57802752);           // 16 reps x 128 f32 = 8192 B
    unsigned int* counter = (unsigned int*)(ws + 57802752 + 8192);
    float* ss = (float*)(ws + 61014528);              // 128 f32

    hipMemsetAsync(stats, 0, 8196, stream);           // stats + counter
    k_attn<<<6272, 128, 0, stream>>>(x, aw, ab, gamma, beta, attn, x2, stats, counter, ss);
    k_bnr<<<12544, 256, 0, stream>>>((unsigned int*)x2, ss);
    k_conv3d<<<1568, 128, 0, stream>>>(x2, w3, b3, gate);
    k_final<<<1792, 448, 0, stream>>>(x, attn, gate, out);
}

// Round 5
// 358.643 us; speedup vs baseline: 1.7093x; 1.7093x over previous
//
#include <hip/hip_runtime.h>
#include <hip/hip_bf16.h>

#define HW 3136      // 56*56
#define CTOT 64
#define NTOT 128
#define BB 16
#define TTT 8

// ---------- helpers ----------
static __device__ __forceinline__ float bf2f(unsigned short u) {
    union { unsigned int ui; float f; } v;
    v.ui = ((unsigned int)u) << 16;
    return v.f;
}
static __device__ __forceinline__ unsigned short f2bf(float f) {
    union { float f; unsigned int u; } v;
    v.f = f;
    unsigned int u = v.u;
    unsigned int r = (u + 0x7fffu + ((u >> 16) & 1u)) >> 16;  // round-nearest-even
    return (unsigned short)r;
}

// ---------- K1: attn = sigmoid(relu(conv2d(x))) FUSED with per-channel stats ----------
// Round-1 proven structure (64 us). Weights gathered inline from aw (k_repack deleted).
// Block 128 = 8 chunks(8ch) x 16 quads; grid = n(128) * tile(49).
__global__ __launch_bounds__(128) void k_attn(const float* __restrict__ x,
                                              const float* __restrict__ aw,
                                              const float* __restrict__ ab,
                                              float* __restrict__ attn,
                                              float* __restrict__ stats) {
    const int tile = blockIdx.x % 49;
    const int n = blockIdx.x / 49;
    const int chunk = threadIdx.x >> 4;    // 0..7
    const int qi = threadIdx.x & 15;       // 0..15
    const int quad = tile * 16 + qi;       // 0..783
    const int q = quad % 14;
    const int h = quad / 14;
    const int w0 = q * 4;

    __shared__ float wl[2304];             // weights [c][dh][kw][head]
    __shared__ float l[8][16][17];         // chunk-reduce scratch (reused for stats)
    __shared__ float4 abuf[4][16];         // attn broadcast [head][quad-in-tile]

    const float* xn = x + (size_t)n * CTOT * HW;
    const int c0 = chunk * 8;

    // branchless row loader: clamped address + validity mask, address-select edges
    auto loadrows = [&](int c, float r[3][6]) {
#pragma unroll
        for (int dh = 0; dh < 3; ++dh) {
            const int hh = h + dh - 1;
            const bool v = (hh >= 0) && (hh < 56);
            const float* row = xn + c * HW + (v ? hh : h) * 56 + w0;
            const float m = v ? 1.f : 0.f;
            const float4 mid = *(const float4*)row;
            const float e0 = row[(q > 0) ? -1 : 0] * ((q > 0) ? m : 0.f);
            const float e5 = row[(q < 13) ? 4 : 3] * ((q < 13) ? m : 0.f);
            r[dh][0] = e0;
            r[dh][1] = mid.x * m; r[dh][2] = mid.y * m;
            r[dh][3] = mid.z * m; r[dh][4] = mid.w * m;
            r[dh][5] = e5;
        }
    };

    float bufA[3][6], bufB[3][6];
    loadrows(c0, bufA);                    // prologue load in flight during staging

    // gather attn weights into LDS, permuted to [c][dh][kw][head]
#pragma unroll
    for (int i = 0; i < 18; ++i) {
        const int idx = threadIdx.x + i * 128;     // 2304 exact
        const int hd = idx & 3;
        const int kw = (idx >> 2) % 3;
        const int dh = (idx / 12) % 3;
        const int c = idx / 36;
        wl[idx] = aw[hd * 576 + c * 9 + dh * 3 + kw];
    }
    __syncthreads();

    float acc[4][4];
#pragma unroll
    for (int hd = 0; hd < 4; ++hd)
#pragma unroll
        for (int j = 0; j < 4; ++j) acc[hd][j] = 0.f;

    float midst[8][4];                     // central-row stash for stats

#pragma unroll
    for (int i = 0; i < 8; ++i) {
        float (*cur)[6] = (i & 1) ? bufB : bufA;
        float (*nxt)[6] = (i & 1) ? bufA : bufB;
        if (i < 7) loadrows(c0 + i + 1, nxt);   // prefetch next channel

        midst[i][0] = cur[1][1]; midst[i][1] = cur[1][2];
        midst[i][2] = cur[1][3]; midst[i][3] = cur[1][4];

        const int c = c0 + i;
#pragma unroll
        for (int dh = 0; dh < 3; ++dh) {
            const float* wb = &wl[c * 36 + dh * 12];
            const float4 wk0 = *(const float4*)(wb);
            const float4 wk1 = *(const float4*)(wb + 4);
            const float4 wk2 = *(const float4*)(wb + 8);
#pragma unroll
            for (int j = 0; j < 4; ++j) {
                const float a0 = cur[dh][j], a1 = cur[dh][j + 1], a2 = cur[dh][j + 2];
                acc[0][j] = fmaf(a0, wk0.x, fmaf(a1, wk1.x, fmaf(a2, wk2.x, acc[0][j])));
                acc[1][j] = fmaf(a0, wk0.y, fmaf(a1, wk1.y, fmaf(a2, wk2.y, acc[1][j])));
                acc[2][j] = fmaf(a0, wk0.z, fmaf(a1, wk1.z, fmaf(a2, wk2.z, acc[2][j])));
                acc[3][j] = fmaf(a0, wk0.w, fmaf(a1, wk1.w, fmaf(a2, wk2.w, acc[3][j])));
            }
        }
    }

    // chunk-reduce attn accumulators through LDS
    float* mine = &l[chunk][qi][0];
#pragma unroll
    for (int hd = 0; hd < 4; ++hd)
#pragma unroll
        for (int j = 0; j < 4; ++j) mine[hd * 4 + j] = acc[hd][j];
    __syncthreads();

    if (threadIdx.x < 64) {
        const int hd = threadIdx.x >> 4;
        const int rq = threadIdx.x & 15;
        float s0 = ab[hd], s1 = s0, s2 = s0, s3 = s0;
#pragma unroll
        for (int cch = 0; cch < 8; ++cch) {
            const float* p = &l[cch][rq][hd * 4];
            s0 += p[0]; s1 += p[1]; s2 += p[2]; s3 += p[3];
        }
        float4 o;
        o.x = s0 > 0.f ? 1.f / (1.f + __expf(-s0)) : 0.5f;
        o.y = s1 > 0.f ? 1.f / (1.f + __expf(-s1)) : 0.5f;
        o.z = s2 > 0.f ? 1.f / (1.f + __expf(-s2)) : 0.5f;
        o.w = s3 > 0.f ? 1.f / (1.f + __expf(-s3)) : 0.5f;
        *(float4*)(attn + (size_t)(n * 4 + hd) * HW + (tile * 16 + rq) * 4) = o;
        abuf[hd][rq] = o;
    }
    __syncthreads();

    // ---- fused stats: v = x*attn over this thread's 8 channels x 4 pixels ----
    const int head = chunk >> 1;           // all 8 channels of a thread share one head
    const float4 a4 = abuf[head][qi];
    float s[8], sq[8];
#pragma unroll
    for (int i = 0; i < 8; ++i) {
        const float v0 = midst[i][0] * a4.x;
        const float v1 = midst[i][1] * a4.y;
        const float v2 = midst[i][2] * a4.z;
        const float v3 = midst[i][3] * a4.w;
        s[i] = v0 + v1 + v2 + v3;
        sq[i] = v0 * v0 + v1 * v1 + v2 * v2 + v3 * v3;
    }
    // per-chunk reduce over the 16 qi threads via LDS (reuse l)
#pragma unroll
    for (int i = 0; i < 8; ++i) { mine[i] = s[i]; mine[8 + i] = sq[i]; }
    __syncthreads();
    {
        const int ch2 = threadIdx.x >> 4;  // chunk being reduced
        const int k = threadIdx.x & 15;    // 0..7 = sum, 8..15 = sumsq
        float t = 0.f;
#pragma unroll
        for (int qq = 0; qq < 16; ++qq) t += l[ch2][qq][k];
        const int cc = ch2 * 8 + (k & 7);
        const int rep = blockIdx.x & 15;
        atomicAdd(&stats[rep * 128 + (k >> 3) * 64 + cc], t);
    }
}

// ---------- K3: finalize scale/shift (reduce 16 replicas) ----------
__global__ void k_finalize(const float* __restrict__ stats,
                           const float* __restrict__ gamma,
                           const float* __restrict__ beta,
                           float* __restrict__ ss) {
    const int c = threadIdx.x;  // 64 threads
    float S = 0.f, Q = 0.f;
#pragma unroll
    for (int r = 0; r < 16; ++r) {
        S += stats[r * 128 + c];
        Q += stats[r * 128 + 64 + c];
    }
    const float cnt = 401408.0f;  // 128*3136
    const float mean = S / cnt;
    const float var = Q / cnt - mean * mean;
    const float scale = gamma[c] * rsqrtf(var + 1e-5f);
    ss[c] = scale;
    ss[64 + c] = beta[c] - mean * scale;
}

// ---------- K4: xbnr = relu(x*attn*scale + shift) -> bf16, attn staged in LDS ----------
// Block = (n, spatial slab of 392 px). attn slab (4 heads) + ss staged in LDS once,
// then 64 channels stream through -> attn fetched ONCE from HBM (was ~16x).
// grid = 128*8 = 1024, block 256. Work: 64ch * 98 float4 = 6272 float4/block.
__global__ __launch_bounds__(256) void k_xbnr(const float* __restrict__ x,
                                              const float* __restrict__ attn,
                                              const float* __restrict__ ss,
                                              unsigned short* __restrict__ xbnr) {
    const int s = blockIdx.x & 7;          // spatial slab
    const int n = blockIdx.x >> 3;         // 0..127
    const int base_sp = s * 392;           // pixel offset

    __shared__ float al[4 * 392];          // attn slab [head][392]
    __shared__ float ssl[128];
    for (int i = threadIdx.x; i < 392; i += 256) {   // 98 float4 per head
        const int hd = i / 98;
        const int j = i - hd * 98;
        ((float4*)al)[hd * 98 + j] =
            *(const float4*)(attn + (size_t)(n * 4 + hd) * HW + base_sp + j * 4);
    }
    if (threadIdx.x < 128) ssl[threadIdx.x] = ss[threadIdx.x];
    __syncthreads();

    for (int wi = threadIdx.x; wi < 6272; wi += 256) {
        const int c = wi / 98;
        const int j = wi - c * 98;
        const float sc = ssl[c], sh = ssl[64 + c];
        const float4 xv = *(const float4*)(x + (size_t)(n * 64 + c) * HW + base_sp + j * 4);
        const float4 av = ((const float4*)al)[(c >> 4) * 98 + j];
        ushort4 o;
        o.x = f2bf(fmaxf(fmaf(xv.x * av.x, sc, sh), 0.f));
        o.y = f2bf(fmaxf(fmaf(xv.y * av.y, sc, sh), 0.f));
        o.z = f2bf(fmaxf(fmaf(xv.z * av.z, sc, sh), 0.f));
        o.w = f2bf(fmaxf(fmaf(xv.w * av.w, sc, sh), 0.f));
        *(ushort4*)(xbnr + (size_t)(n * 64 + c) * HW + base_sp + j * 4) = o;
    }
}

// ---------- K5: grouped conv3d + bias + tanh -> gate (LDS chunk-reduction) ----------
// Round-1 structure + weights staged in LDS (pins codegen: no global loads in loop).
// Block 128 = 8 ic-chunks x 16 quads. Grid = b(16) * oc(2) * tile(49).
__global__ __launch_bounds__(128) void k_conv3d(const unsigned short* __restrict__ xbnr,
                                                const float* __restrict__ w3,
                                                const float* __restrict__ b3,
                                                float* __restrict__ gate) {
    const int tile = blockIdx.x % 49;
    const int oc = (blockIdx.x / 49) & 1;
    const int b = blockIdx.x / 98;
    const int chunk = threadIdx.x >> 4;    // 0..7
    const int qi = threadIdx.x & 15;       // 0..15
    const int quad = tile * 16 + qi;       // 0..783
    const int q = quad % 14;
    const int h = quad / 14;
    const int w0 = q * 4;

    __shared__ float wlds[864];            // this oc's 32 ic x 27 weights
    for (int i = threadIdx.x; i < 864; i += 128) wlds[i] = w3[oc * 864 + i];
    __syncthreads();

    float acc[8][4];
#pragma unroll
    for (int t = 0; t < 8; ++t)
#pragma unroll
        for (int j = 0; j < 4; ++j) acc[t][j] = 0.f;

    const int ic0 = chunk * 4;
    for (int ic = ic0; ic < ic0 + 4; ++ic) {
        const int c = oc * 32 + ic;
        const unsigned short* cbase = xbnr + (size_t)(b * 8 * 64 + c) * HW;
        const float* wic = &wlds[ic * 27];  // (dt, dh, dw)
#pragma unroll
        for (int tt = 0; tt < 8; ++tt) {
            const unsigned short* plane = cbase + (size_t)tt * (64 * HW);
#pragma unroll
            for (int dh = 0; dh < 3; ++dh) {
                const int hh = h + dh - 1;
                if (hh < 0 || hh >= 56) continue;
                const unsigned short* row = plane + hh * 56 + w0;
                const ushort4 mid = *(const ushort4*)row;
                const float f0 = (q > 0) ? bf2f(row[-1]) : 0.f;
                const float f1 = bf2f(mid.x), f2 = bf2f(mid.y);
                const float f3 = bf2f(mid.z), f4 = bf2f(mid.w);
                const float f5 = (q < 13) ? bf2f(row[4]) : 0.f;
#pragma unroll
                for (int dt = 0; dt < 3; ++dt) {
                    const int t = tt + 1 - dt;   // out[t] += in[t+dt-1]*w[dt]
                    if (t < 0 || t > 7) continue;
                    const float* wp = wic + dt * 9 + dh * 3;
                    const float wa = wp[0], wb = wp[1], wc = wp[2];
                    acc[t][0] = fmaf(f0, wa, fmaf(f1, wb, fmaf(f2, wc, acc[t][0])));
                    acc[t][1] = fmaf(f1, wa, fmaf(f2, wb, fmaf(f3, wc, acc[t][1])));
                    acc[t][2] = fmaf(f2, wa, fmaf(f3, wb, fmaf(f4, wc, acc[t][2])));
                    acc[t][3] = fmaf(f3, wa, fmaf(f4, wb, fmaf(f5, wc, acc[t][3])));
                }
            }
        }
    }

    // LDS reduction over chunks. Layout: [chunk][qi][9 float4] (pad 8->9 breaks bank alias)
    __shared__ float4 l4[8 * 16 * 9];
    float4* mine = &l4[(chunk * 16 + qi) * 9];
#pragma unroll
    for (int t = 0; t < 8; ++t) {
        float4 v;
        v.x = acc[t][0]; v.y = acc[t][1]; v.z = acc[t][2]; v.w = acc[t][3];
        mine[t] = v;
    }
    __syncthreads();

    const int rt = threadIdx.x >> 4;   // t of this thread's output
    const int rq = threadIdx.x & 15;   // quad within tile
    float4 s = l4[(0 * 16 + rq) * 9 + rt];
#pragma unroll
    for (int c = 1; c < 8; ++c) {
        const float4 v = l4[(c * 16 + rq) * 9 + rt];
        s.x += v.x; s.y += v.y; s.z += v.z; s.w += v.w;
    }
    const float bb = b3[oc];
    float4 o;
    o.x = tanhf(s.x + bb);
    o.y = tanhf(s.y + bb);
    o.z = tanhf(s.z + bb);
    o.w = tanhf(s.w + bb);
    const int outquad = tile * 16 + rq;
    *(float4*)(gate + (size_t)((b * 2 + oc) * 8 + rt) * HW + outquad * 4) = o;
}

// ---------- K6: final gating + temporal shift + interleave ----------
// Round-1 proven version. grid 3136, block 256; thread = (b, c_out, h, 4w) x all 8 t
__global__ __launch_bounds__(256) void k_final(const float* __restrict__ x,
                                               const float* __restrict__ attn,
                                               const float* __restrict__ gate,
                                               float* __restrict__ out) {
    const int gt = blockIdx.x * 256 + threadIdx.x;  // 802816 exact
    const int q = gt % 14;
    int r = gt / 14;
    const int h = r % 56;
    r /= 56;
    const int co = r & 63;
    const int b = r >> 6;
    const int sp = h * 56 + q * 4;

    int cs, grp;
    if (co < 32) {
        cs = ((co & 1) << 4) | (co >> 1);
        grp = 0;
    } else {
        const int cc = co - 32;
        cs = 32 + (((cc & 1) << 4) | (cc >> 1));
        grp = 1;
    }
    const int head = cs >> 4;

    float4 x2[8], g[8];
#pragma unroll
    for (int t = 0; t < 8; ++t) {
        const int n = b * 8 + t;
        const float4 xv = *(const float4*)(x + (size_t)(n * 64 + cs) * HW + sp);
        const float4 av = *(const float4*)(attn + (size_t)(n * 4 + head) * HW + sp);
        const float4 gv = *(const float4*)(gate + (size_t)((b * 2 + grp) * 8 + t) * HW + sp);
        x2[t].x = xv.x * av.x;
        x2[t].y = xv.y * av.y;
        x2[t].z = xv.z * av.z;
        x2[t].w = xv.w * av.w;
        g[t] = gv;
    }
#pragma unroll
    for (int t = 0; t < 8; ++t) {
        float4 o;
        o.x = x2[t].x * (1.f - g[t].x);
        o.y = x2[t].y * (1.f - g[t].y);
        o.z = x2[t].z * (1.f - g[t].z);
        o.w = x2[t].w * (1.f - g[t].w);
        if (grp == 0) {
            if (t < 7) {
                o.x += x2[t + 1].x * g[t + 1].x;
                o.y += x2[t + 1].y * g[t + 1].y;
                o.z += x2[t + 1].z * g[t + 1].z;
                o.w += x2[t + 1].w * g[t + 1].w;
            }
        } else {
            if (t > 0) {
                o.x += x2[t - 1].x * g[t - 1].x;
                o.y += x2[t - 1].y * g[t - 1].y;
                o.z += x2[t - 1].z * g[t - 1].z;
                o.w += x2[t - 1].w * g[t - 1].w;
            }
        }
        *(float4*)(out + (size_t)((b * 8 + t) * 64 + co) * HW + sp) = o;
    }
}

// ---------- launch ----------
extern "C" void kernel_launch(void* const* d_in, const int* in_sizes, int n_in,
                              void* d_out, int out_size, void* d_ws, size_t ws_size,
                              hipStream_t stream) {
    const float* x = (const float*)d_in[0];
    const float* aw = (const float*)d_in[1];
    const float* ab = (const float*)d_in[2];
    const float* gamma = (const float*)d_in[3];
    const float* beta = (const float*)d_in[4];
    const float* w3 = (const float*)d_in[5];
    const float* b3 = (const float*)d_in[6];
    float* out = (float*)d_out;

    char* ws = (char*)d_ws;
    // layout: xbnr bf16 [0, 51380224) | attn f32 | gate f32 (stats aliases its head,
    // lifetimes disjoint: stats dead before k_conv3d writes gate) | ss
    unsigned short* xbnr = (unsigned short*)ws;
    float* attn = (float*)(ws + 51380224);            // 128*4*3136 f32 = 6422528 B
    float* gate = (float*)(ws + 57802752);            // 16*2*8*3136 f32 = 3211264 B
    float* stats = (float*)(ws + 57802752);           // 16 reps x 128 f32 = 8192 B (aliases gate)
    float* ss = (float*)(ws + 61014528);              // 128 f32

    hipMemsetAsync(stats, 0, 8192, stream);
    k_attn<<<6272, 128, 0, stream>>>(x, aw, ab, attn, stats);
    k_finalize<<<1, 64, 0, stream>>>(stats, gamma, beta, ss);
    k_xbnr<<<1024, 256, 0, stream>>>(x, attn, ss, xbnr);
    k_conv3d<<<1568, 128, 0, stream>>>(xbnr, w3, b3, gate);
    k_final<<<3136, 256, 0, stream>>>(x, attn, gate, out);
}